// Round 1
// baseline (738.989 us; speedup 1.0000x reference)
//
#include <hip/hip_runtime.h>
#include <math.h>

#define BB 2048
#define TT 200
#define BN_EPS 1e-3f
#define MASKV (-4294967295.0f)
#define INV_SQRTK 0.08838834764831845f

// ---------------------------------------------------------------------------
// K1: per-batch-row DIN attention.
//   - q = item_join[b] (128)
//   - W1eff[k][j] = W1[128+k][j] - W1[256+k][j] + q[k]*W1[384+k][j]
//   - c[j] = b1[j] + sum_k q[k]*(W1[k][j] + W1[256+k][j])
//   - scores -> mask -> /sqrt(K) -> softmax -> hist_attn = attn @ hist_join
// 512 threads, ~127KB LDS (1 block/CU, 2 waves/SIMD).
// ---------------------------------------------------------------------------
__global__ __launch_bounds__(512) void k1_attn(
    const int* __restrict__ item, const int* __restrict__ history,
    const int* __restrict__ length, const int* __restrict__ cate_list,
    const float* __restrict__ item_table, const float* __restrict__ cate_table,
    const float* __restrict__ W1, const float* __restrict__ b1,
    const float* __restrict__ W2, const float* __restrict__ b2,
    const float* __restrict__ W3, const float* __restrict__ b3,
    float* __restrict__ hist_attn)
{
    __shared__ float sW1t[80][132];     // W1eff transposed [j][k], pad 132
    __shared__ float sHbuf[128 * 132];  // hist rows [r][132]; overlaid h1 [r][84]
    __shared__ float sW2t[40][84];      // W2 transposed [j2][j]
    __shared__ float sQ[128];
    __shared__ float sCc[80];
    __shared__ float sW3[40];
    __shared__ float sB2[40];
    __shared__ float sScore[256];
    __shared__ int   sHist[TT];
    __shared__ int   sCid[TT];
    __shared__ float sRed[8];
    __shared__ float sMS[2];
    __shared__ float sB3;

    const int b   = blockIdx.x;
    const int tid = threadIdx.x;
    const int it  = item[b];
    const int len = length[b];

    // ---- Phase A: q, hist indices, small weights ----
    if (tid < 64)       sQ[tid] = item_table[it * 64 + tid];
    else if (tid < 128) sQ[tid] = cate_table[cate_list[it] * 64 + (tid - 64)];
    if (tid < TT) { int h = history[b * TT + tid]; sHist[tid] = h; sCid[tid] = cate_list[h]; }
    if (tid < 40) { sW3[tid] = W3[tid]; sB2[tid] = b2[tid]; }
    if (tid == 0) sB3 = b3[0];
    __syncthreads();

    // W1eff (coalesced: consecutive tid -> consecutive j for same k)
    for (int i = tid; i < 80 * 128; i += 512) {
        int k = i / 80, j = i - k * 80;
        sW1t[j][k] = W1[(128 + k) * 80 + j] - W1[(256 + k) * 80 + j]
                   + sQ[k] * W1[(384 + k) * 80 + j];
    }
    if (tid < 80) {
        float c = b1[tid];
        for (int k = 0; k < 128; ++k)
            c = fmaf(sQ[k], W1[k * 80 + tid] + W1[(256 + k) * 80 + tid], c);
        sCc[tid] = c;
    }
    for (int i = tid; i < 40 * 80; i += 512) {
        int j2 = i / 80, j = i - j2 * 80;
        sW2t[j2][j] = W2[j * 40 + j2];
    }

    const int j0 = tid & 15;   // 16 j-groups of 5
    const int tg = tid >> 4;   // 32 t-groups of 4  -> 128 t per pass
    const int l2g = tid & 3;   // layer2: 4 j2-groups of 10
    const int l2t = tid >> 2;  // 0..127

    for (int t0 = 0; t0 < TT; t0 += 128) {
        __syncthreads();
        // stage hist rows: 4 threads/row, 32 floats each
        {
            int r = tid >> 2, s = tid & 3;
            int t = t0 + r;
            if (t < TT) {
                const float* src = (s < 2) ? (item_table + sHist[t] * 64 + s * 32)
                                           : (cate_table + sCid[t] * 64 + (s - 2) * 32);
                float* dst = &sHbuf[r * 132 + ((s < 2) ? s * 32 : 64 + (s - 2) * 32)];
#pragma unroll
                for (int q4 = 0; q4 < 8; ++q4)
                    *(float4*)(dst + q4 * 4) = *(const float4*)(src + q4 * 4);
            }
        }
        __syncthreads();

        // layer 1: per-thread 4t x 5j register tile
        float acc[4][5];
#pragma unroll
        for (int p = 0; p < 4; ++p)
#pragma unroll
            for (int m = 0; m < 5; ++m) acc[p][m] = 0.f;
        {
            const int r0 = tg * 4;
            for (int k = 0; k < 128; k += 4) {
                float4 h0 = *(float4*)&sHbuf[(r0 + 0) * 132 + k];
                float4 h1v = *(float4*)&sHbuf[(r0 + 1) * 132 + k];
                float4 h2v = *(float4*)&sHbuf[(r0 + 2) * 132 + k];
                float4 h3v = *(float4*)&sHbuf[(r0 + 3) * 132 + k];
#pragma unroll
                for (int m = 0; m < 5; ++m) {
                    float4 w = *(float4*)&sW1t[j0 * 5 + m][k];
                    acc[0][m] = fmaf(w.x, h0.x, fmaf(w.y, h0.y, fmaf(w.z, h0.z, fmaf(w.w, h0.w, acc[0][m]))));
                    acc[1][m] = fmaf(w.x, h1v.x, fmaf(w.y, h1v.y, fmaf(w.z, h1v.z, fmaf(w.w, h1v.w, acc[1][m]))));
                    acc[2][m] = fmaf(w.x, h2v.x, fmaf(w.y, h2v.y, fmaf(w.z, h2v.z, fmaf(w.w, h2v.w, acc[2][m]))));
                    acc[3][m] = fmaf(w.x, h3v.x, fmaf(w.y, h3v.y, fmaf(w.z, h3v.z, fmaf(w.w, h3v.w, acc[3][m]))));
                }
            }
        }
        __syncthreads();   // all sH reads done before overlay write
        {
#pragma unroll
            for (int p = 0; p < 4; ++p) {
                int t = t0 + tg * 4 + p;
                if (t < TT) {
#pragma unroll
                    for (int m = 0; m < 5; ++m) {
                        int j = j0 * 5 + m;
                        float pre = acc[p][m] + sCc[j];
                        sHbuf[(tg * 4 + p) * 84 + j] = 1.f / (1.f + __expf(-pre));
                    }
                }
            }
        }
        __syncthreads();

        // layer 2 (sigmoid) + layer 3 (dot with W3) -> score
        {
            int t = t0 + l2t;
            if (t < TT) {
                float a2[10];
#pragma unroll
                for (int u = 0; u < 10; ++u) a2[u] = 0.f;
                for (int j = 0; j < 80; j += 4) {
                    float4 hv = *(float4*)&sHbuf[l2t * 84 + j];
#pragma unroll
                    for (int u = 0; u < 10; ++u) {
                        float4 w = *(float4*)&sW2t[l2g * 10 + u][j];
                        a2[u] = fmaf(w.x, hv.x, fmaf(w.y, hv.y, fmaf(w.z, hv.z, fmaf(w.w, hv.w, a2[u]))));
                    }
                }
                float part = 0.f;
#pragma unroll
                for (int u = 0; u < 10; ++u) {
                    int j2 = l2g * 10 + u;
                    float h2s = 1.f / (1.f + __expf(-(a2[u] + sB2[j2])));
                    part = fmaf(h2s, sW3[j2], part);
                }
                part += __shfl_xor(part, 1);
                part += __shfl_xor(part, 2);
                if (l2g == 0) sScore[t] = part + sB3;
            }
        }
    }
    __syncthreads();

    // ---- Phase C: masked, scaled softmax over T ----
    int t = tid;
    float sc;
    if (t < TT) {
        float raw = sScore[t];
        if (t >= len) raw = MASKV;
        sc = raw * INV_SQRTK;
    } else {
        sc = -3.0e38f;
    }
    float mx = sc;
#pragma unroll
    for (int o = 32; o > 0; o >>= 1) mx = fmaxf(mx, __shfl_xor(mx, o));
    if ((tid & 63) == 0) sRed[tid >> 6] = mx;
    __syncthreads();
    if (tid == 0) {
        float m2 = sRed[0];
        for (int w = 1; w < 8; ++w) m2 = fmaxf(m2, sRed[w]);
        sMS[0] = m2;
    }
    __syncthreads();
    mx = sMS[0];
    float e = (t < TT) ? __expf(sc - mx) : 0.f;
    float sum = e;
#pragma unroll
    for (int o = 32; o > 0; o >>= 1) sum += __shfl_xor(sum, o);
    if ((tid & 63) == 0) sRed[tid >> 6] = sum;
    __syncthreads();
    if (tid == 0) {
        float s2 = 0.f;
        for (int w = 0; w < 8; ++w) s2 += sRed[w];
        sMS[1] = s2;
    }
    __syncthreads();
    float inv = 1.f / sMS[1];
    if (t < TT) sScore[t] = e * inv;
    __syncthreads();

    // ---- Phase D: hist_attn[k] = sum_t attn[t] * hist_join[t][k] (re-gather) ----
    const int kk = tid & 127;
    const int g  = tid >> 7;  // 0..3
    float wacc = 0.f;
    for (int tt = g; tt < TT; tt += 4) {
        float a = sScore[tt];
        float v = (kk < 64) ? item_table[sHist[tt] * 64 + kk]
                            : cate_table[sCid[tt] * 64 + (kk - 64)];
        wacc = fmaf(a, v, wacc);
    }
    sHbuf[g * 128 + kk] = wacc;
    __syncthreads();
    if (tid < 128) {
        float tot = sHbuf[tid] + sHbuf[128 + tid] + sHbuf[256 + tid] + sHbuf[384 + tid];
        hist_attn[b * 128 + tid] = tot;
    }
}

// ---------------------------------------------------------------------------
// K2: column sums / sumsq of hist_attn [2048 x 128] -> stats[0:128], [128:256]
// ---------------------------------------------------------------------------
__global__ __launch_bounds__(256) void k2_hstats(const float* __restrict__ hist_attn,
                                                 float* __restrict__ stats)
{
    const int tid = threadIdx.x;
    const int k   = tid & 127;
    const int rh  = tid >> 7;
    const int r0  = blockIdx.x * 32;
    float s = 0.f, s2 = 0.f;
    for (int r = r0 + rh; r < r0 + 32; r += 2) {
        float v = hist_attn[r * 128 + k];
        s += v;
        s2 = fmaf(v, v, s2);
    }
    atomicAdd(&stats[k], s);
    atomicAdd(&stats[128 + k], s2);
}

// ---------------------------------------------------------------------------
// K3: hist_hid = BN(hist_attn)@hist_W + hist_b ; assemble join ; join stats
// ---------------------------------------------------------------------------
__global__ __launch_bounds__(256) void k3_histfc_join(
    const float* __restrict__ hist_attn, const float* __restrict__ hstats,
    const float* __restrict__ hgamma, const float* __restrict__ hbeta,
    const float* __restrict__ histW, const float* __restrict__ histb,
    const int* __restrict__ user, const int* __restrict__ item,
    const int* __restrict__ cate_list,
    const float* __restrict__ user_table, const float* __restrict__ item_table,
    const float* __restrict__ cate_table,
    float* __restrict__ jbuf, float* __restrict__ jstats)
{
    __shared__ float sWs[128][132];
    __shared__ float sX[8][132];
    __shared__ float sCs[128];
    __shared__ float sScale[128];
    __shared__ float sShift[128];

    const int tid = threadIdx.x;
    const int r0  = blockIdx.x * 8;
    if (tid < 128) {
        float m  = hstats[tid] * (1.f / 2048.f);
        float v  = hstats[128 + tid] * (1.f / 2048.f) - m * m;
        float rs = rsqrtf(v + BN_EPS);
        float scv = hgamma[tid] * rs;
        sScale[tid] = scv;
        sShift[tid] = hbeta[tid] - m * scv;
    }
    __syncthreads();
    for (int i = tid; i < 128 * 128; i += 256) {
        int k = i >> 7;
        sWs[k][i & 127] = sScale[k] * histW[i];
    }
    if (tid < 128) {
        float c = histb[tid];
        for (int k = 0; k < 128; ++k) c = fmaf(sShift[k], histW[k * 128 + tid], c);
        sCs[tid] = c;
    }
    for (int i = tid; i < 8 * 128; i += 256) {
        int r = i >> 7;
        sX[r][i & 127] = hist_attn[(r0 + r) * 128 + (i & 127)];
    }
    __syncthreads();

    const int j  = tid & 127;
    const int rh = tid >> 7;
    float su0 = 0.f, su1 = 0.f, su2 = 0.f, sq0 = 0.f, sq1 = 0.f, sq2 = 0.f;
    for (int r = rh; r < 8; r += 2) {
        int row = r0 + r;
        float o = sCs[j];
        for (int k = 0; k < 128; ++k) o = fmaf(sX[r][k], sWs[k][j], o);
        int u    = user[row];
        float ue = user_table[u * 128 + j];
        int itv  = item[row];
        float qv = (j < 64) ? item_table[itv * 64 + j]
                            : cate_table[cate_list[itv] * 64 + (j - 64)];
        jbuf[row * 384 + j]       = ue;
        jbuf[row * 384 + 128 + j] = qv;
        jbuf[row * 384 + 256 + j] = o;
        su0 += ue; sq0 = fmaf(ue, ue, sq0);
        su1 += qv; sq1 = fmaf(qv, qv, sq1);
        su2 += o;  sq2 = fmaf(o, o, sq2);
    }
    atomicAdd(&jstats[j], su0);            atomicAdd(&jstats[384 + j], sq0);
    atomicAdd(&jstats[128 + j], su1);      atomicAdd(&jstats[384 + 128 + j], sq1);
    atomicAdd(&jstats[256 + j], su2);      atomicAdd(&jstats[384 + 256 + j], sq2);
}

// ---------------------------------------------------------------------------
// K4: x = BN(join) ; pre1 = x@fc1_W + b ; pre1 column stats
// ---------------------------------------------------------------------------
__global__ __launch_bounds__(256) void k4_fc1(
    const float* __restrict__ jbuf, const float* __restrict__ jstats,
    const float* __restrict__ fgamma, const float* __restrict__ fbeta,
    const float* __restrict__ fc1W, const float* __restrict__ fc1b,
    float* __restrict__ pre1, float* __restrict__ p1stats)
{
    __shared__ float sXn[8][388];
    __shared__ float sScale[384];
    __shared__ float sShift[384];
    const int tid = threadIdx.x;
    const int r0  = blockIdx.x * 8;
    for (int c = tid; c < 384; c += 256) {
        float m  = jstats[c] * (1.f / 2048.f);
        float v  = jstats[384 + c] * (1.f / 2048.f) - m * m;
        float rs = rsqrtf(v + BN_EPS);
        float scv = fgamma[c] * rs;
        sScale[c] = scv;
        sShift[c] = fbeta[c] - m * scv;
    }
    __syncthreads();
    for (int i = tid; i < 8 * 384; i += 256) {
        int r = i / 384, c = i - r * 384;
        sXn[r][c] = jbuf[(r0 + r) * 384 + c] * sScale[c] + sShift[c];
    }
    __syncthreads();
    const int j1 = tid % 80;
    const int rg = tid / 80;
    if (rg < 3) {
        float su = 0.f, sq = 0.f;
        for (int r = rg; r < 8; r += 3) {
            float a = fc1b[j1];
            for (int c = 0; c < 384; ++c) a = fmaf(sXn[r][c], fc1W[c * 80 + j1], a);
            pre1[(r0 + r) * 80 + j1] = a;
            su += a;
            sq = fmaf(a, a, sq);
        }
        atomicAdd(&p1stats[j1], su);
        atomicAdd(&p1stats[80 + j1], sq);
    }
}

// ---------------------------------------------------------------------------
// K5: x1 = dice(pre1) ; pre2 = x1@fc2_W + b ; pre2 column stats
// ---------------------------------------------------------------------------
__global__ __launch_bounds__(256) void k5_fc2(
    const float* __restrict__ pre1, const float* __restrict__ p1stats,
    const float* __restrict__ d1a, const float* __restrict__ d1b,
    const float* __restrict__ fc2W, const float* __restrict__ fc2b,
    float* __restrict__ pre2, float* __restrict__ p2stats)
{
    __shared__ float sX1[8][84];
    __shared__ float sM[80], sRs[80], sA[80], sBt[80];
    const int tid = threadIdx.x;
    const int r0  = blockIdx.x * 8;
    if (tid < 80) {
        float m = p1stats[tid] * (1.f / 2048.f);
        float v = p1stats[80 + tid] * (1.f / 2048.f) - m * m;
        sM[tid]  = m;
        sRs[tid] = rsqrtf(v + BN_EPS);
        sA[tid]  = d1a[tid];
        sBt[tid] = d1b[tid];
    }
    __syncthreads();
    for (int i = tid; i < 8 * 80; i += 256) {
        int r = i / 80, c = i - r * 80;
        float x  = pre1[(r0 + r) * 80 + c];
        float xn = (x - sM[c]) * sRs[c];
        float p  = 1.f / (1.f + __expf(-sBt[c] * xn));
        sX1[r][c] = x * (p + sA[c] * (1.f - p));
    }
    __syncthreads();
    const int j2 = tid % 40;
    const int rg = tid / 40;
    if (rg < 6) {
        float su = 0.f, sq = 0.f;
        for (int r = rg; r < 8; r += 6) {
            float a = fc2b[j2];
            for (int c = 0; c < 80; ++c) a = fmaf(sX1[r][c], fc2W[c * 40 + j2], a);
            pre2[(r0 + r) * 40 + j2] = a;
            su += a;
            sq = fmaf(a, a, sq);
        }
        atomicAdd(&p2stats[j2], su);
        atomicAdd(&p2stats[40 + j2], sq);
    }
}

// ---------------------------------------------------------------------------
// K6: x2 = dice(pre2) ; out = x2@fc3_W + b3 + item_bias ; logit = sigmoid(out)
// ---------------------------------------------------------------------------
__global__ __launch_bounds__(256) void k6_out(
    const float* __restrict__ pre2, const float* __restrict__ p2stats,
    const float* __restrict__ d2a, const float* __restrict__ d2b,
    const float* __restrict__ fc3W, const float* __restrict__ fc3b,
    const float* __restrict__ item_bias, const int* __restrict__ item,
    float* __restrict__ outp)
{
    __shared__ float sM[40], sRs[40], sA[40], sBt[40], sW[40];
    __shared__ float sB3v;
    const int tid = threadIdx.x;
    if (tid < 40) {
        float m = p2stats[tid] * (1.f / 2048.f);
        float v = p2stats[40 + tid] * (1.f / 2048.f) - m * m;
        sM[tid]  = m;
        sRs[tid] = rsqrtf(v + BN_EPS);
        sA[tid]  = d2a[tid];
        sBt[tid] = d2b[tid];
        sW[tid]  = fc3W[tid];
    }
    if (tid == 0) sB3v = fc3b[0];
    __syncthreads();
    const int r = blockIdx.x * 256 + tid;
    float a = sB3v;
    for (int c = 0; c < 40; ++c) {
        float x  = pre2[r * 40 + c];
        float xn = (x - sM[c]) * sRs[c];
        float p  = 1.f / (1.f + __expf(-sBt[c] * xn));
        float x2 = x * (p + sA[c] * (1.f - p));
        a = fmaf(x2, sW[c], a);
    }
    a += item_bias[item[r]];
    outp[r]        = a;
    outp[BB + r]   = 1.f / (1.f + __expf(-a));
}

// ---------------------------------------------------------------------------
extern "C" void kernel_launch(void* const* d_in, const int* in_sizes, int n_in,
                              void* d_out, int out_size, void* d_ws, size_t ws_size,
                              hipStream_t stream)
{
    const int*   user       = (const int*)d_in[0];
    const int*   item       = (const int*)d_in[1];
    const int*   history    = (const int*)d_in[2];
    const int*   length     = (const int*)d_in[3];
    const int*   cate_list  = (const int*)d_in[4];
    const float* user_table = (const float*)d_in[5];
    const float* item_table = (const float*)d_in[6];
    const float* cate_table = (const float*)d_in[7];
    const float* item_bias  = (const float*)d_in[8];
    const float* att_W1 = (const float*)d_in[9];
    const float* att_b1 = (const float*)d_in[10];
    const float* att_W2 = (const float*)d_in[11];
    const float* att_b2 = (const float*)d_in[12];
    const float* att_W3 = (const float*)d_in[13];
    const float* att_b3 = (const float*)d_in[14];
    const float* hgam   = (const float*)d_in[15];
    const float* hbet   = (const float*)d_in[16];
    const float* histW  = (const float*)d_in[17];
    const float* histb  = (const float*)d_in[18];
    const float* fgam   = (const float*)d_in[19];
    const float* fbet   = (const float*)d_in[20];
    const float* fc1W   = (const float*)d_in[21];
    const float* fc1b   = (const float*)d_in[22];
    const float* d1a    = (const float*)d_in[23];
    const float* d1b    = (const float*)d_in[24];
    const float* fc2W   = (const float*)d_in[25];
    const float* fc2b   = (const float*)d_in[26];
    const float* d2a    = (const float*)d_in[27];
    const float* d2b    = (const float*)d_in[28];
    const float* fc3W   = (const float*)d_in[29];
    const float* fc3b   = (const float*)d_in[30];

    float* ws        = (float*)d_ws;
    float* hist_attn = ws;                    // 2048*128   = 262144
    float* jbuf      = hist_attn + 262144;    // 2048*384   = 786432
    float* pre1      = jbuf + 786432;         // 2048*80    = 163840
    float* pre2      = pre1 + 163840;         // 2048*40    = 81920
    float* stats     = pre2 + 81920;          // 1264 floats total
    float* hstats  = stats;                   // 256
    float* jstats  = stats + 256;             // 768
    float* p1stats = jstats + 768;            // 160
    float* p2stats = p1stats + 160;           // 80

    hipMemsetAsync(stats, 0, 1264 * sizeof(float), stream);

    k1_attn<<<BB, 512, 0, stream>>>(item, history, length, cate_list,
        item_table, cate_table, att_W1, att_b1, att_W2, att_b2, att_W3, att_b3,
        hist_attn);
    k2_hstats<<<64, 256, 0, stream>>>(hist_attn, hstats);
    k3_histfc_join<<<256, 256, 0, stream>>>(hist_attn, hstats, hgam, hbet,
        histW, histb, user, item, cate_list, user_table, item_table, cate_table,
        jbuf, jstats);
    k4_fc1<<<256, 256, 0, stream>>>(jbuf, jstats, fgam, fbet, fc1W, fc1b,
        pre1, p1stats);
    k5_fc2<<<256, 256, 0, stream>>>(pre1, p1stats, d1a, d1b, fc2W, fc2b,
        pre2, p2stats);
    k6_out<<<8, 256, 0, stream>>>(pre2, p2stats, d2a, d2b, fc3W, fc3b,
        item_bias, item, (float*)d_out);
}

// Round 2
// 471.502 us; speedup vs baseline: 1.5673x; 1.5673x over previous
//
#include <hip/hip_runtime.h>
#include <math.h>

#define BB 2048
#define TT 200
#define BN_EPS 1e-3f
#define MASKV (-4294967295.0f)
#define INV_SQRTK 0.08838834764831845f

typedef short bfrag __attribute__((ext_vector_type(8)));
typedef float f32x4 __attribute__((ext_vector_type(4)));

__device__ __forceinline__ unsigned short f2b(float x) {
    union { float f; unsigned u; } v; v.f = x;
    unsigned r = (v.u + 0x7fffu + ((v.u >> 16) & 1u)) >> 16;
    return (unsigned short)r;
}
__device__ __forceinline__ float b2f(unsigned short u) {
    union { unsigned u; float f; } v; v.u = ((unsigned)u) << 16; return v.f;
}
__device__ __forceinline__ float sigm(float x) { return 1.f / (1.f + __expf(-x)); }

// ---------------------------------------------------------------------------
// k0: block-invariant weight prep.
//  W1bcT[j*128+k] = W1[(128+k)*80+j] - W1[(256+k)*80+j]   (f32, transposed)
//  W1dT [j*128+k] = W1[(384+k)*80+j]
//  W1ac [k*80+j]  = W1[k*80+j] + W1[(256+k)*80+j]         (original layout)
//  fc1WT[j*384+c] = fc1W[c*80+j] ; fc2WT[j*80+c] = fc2W[c*40+j]
// ---------------------------------------------------------------------------
__global__ __launch_bounds__(256) void k0_prep(
    const float* __restrict__ W1, const float* __restrict__ fc1W,
    const float* __restrict__ fc2W, float* __restrict__ prep)
{
    const int gid = blockIdx.x * 256 + threadIdx.x;
    const int stride = gridDim.x * 256;
    float* W1bcT = prep;
    float* W1dT  = prep + 10240;
    float* W1ac  = prep + 20480;
    float* fc1WT = prep + 30720;
    float* fc2WT = prep + 61440;
    for (int i = gid; i < 10240; i += stride) {
        int j = i >> 7, k = i & 127;
        float wa = W1[k * 80 + j];
        float wb = W1[(128 + k) * 80 + j];
        float wc = W1[(256 + k) * 80 + j];
        float wd = W1[(384 + k) * 80 + j];
        W1bcT[i] = wb - wc;
        W1dT[i]  = wd;
        W1ac[k * 80 + j] = wa + wc;
    }
    for (int i = gid; i < 30720; i += stride) { int j = i / 384, c = i - j * 384; fc1WT[i] = fc1W[c * 80 + j]; }
    for (int i = gid; i < 3200;  i += stride) { int j = i / 80,  c = i - j * 80;  fc2WT[i] = fc2W[c * 40 + j]; }
}

// ---------------------------------------------------------------------------
// K1: DIN attention via MFMA. One block per batch row, 512 threads (8 waves).
//  layer1: [208x128]bf16 @ W1eff^T[80x128]bf16 -> sigmoid -> h1 [208x80]bf16
//  layer2: h1 @ W2[80x40] -> sigmoid -> dot W3 -> scores -> softmax
//  phase D: hist_attn = attn @ hist_rows (from staged bf16 LDS)
//  + fold hist_attn column stats (K2) into epilogue atomics.
// ---------------------------------------------------------------------------
__global__ __launch_bounds__(512) void k1_attn(
    const int* __restrict__ item, const int* __restrict__ history,
    const int* __restrict__ length, const int* __restrict__ cate_list,
    const float* __restrict__ item_table, const float* __restrict__ cate_table,
    const float* __restrict__ W1bcT, const float* __restrict__ W1dT,
    const float* __restrict__ W1ac,
    const float* __restrict__ b1, const float* __restrict__ W2,
    const float* __restrict__ b2, const float* __restrict__ W3,
    const float* __restrict__ b3,
    float* __restrict__ hist_attn, float* __restrict__ hstats)
{
    __shared__ unsigned short sA[208 * 136];   // hist rows bf16, row stride 136 (272B, 16B-aligned)
    __shared__ unsigned short sU[208 * 104];   // union: W1eff^T [80][136] -> h1 [208][104]
    __shared__ unsigned short sW2[48 * 104];   // W2^T [n][k], zero-padded
    __shared__ float sQ[128], sCc[80], sCp[480], sPd[1024], sScore[256];
    __shared__ float sB2[48], sW3f[48];
    __shared__ int   sHist[TT], sCid[TT];
    __shared__ float sRed[8], sMS[2], sB3s;

    const int b   = blockIdx.x;
    const int tid = threadIdx.x;
    const int it  = item[b];
    const int len = length[b];

    // ---- Phase A ----
    if (tid < 64)       sQ[tid] = item_table[(size_t)it * 64 + tid];
    else if (tid < 128) sQ[tid] = cate_table[(size_t)cate_list[it] * 64 + (tid - 64)];
    if (tid < TT) { int h = history[(size_t)b * TT + tid]; sHist[tid] = h; sCid[tid] = cate_list[h]; }
    if (tid < 48) { sB2[tid] = (tid < 40) ? b2[tid] : 0.f; sW3f[tid] = (tid < 40) ? W3[tid] : 0.f; }
    if (tid < 256) sScore[tid] = 0.f;
    if (tid == 0) sB3s = b3[0];
    for (int i = tid; i < 8 * 136; i += 512) sA[200 * 136 + i] = 0;       // zero pad rows
    for (int i = tid; i < 48 * 104; i += 512) {
        int n = i / 104, k = i - n * 104;
        float v = (n < 40 && k < 80) ? W2[k * 40 + n] : 0.f;
        sW2[i] = f2b(v);
    }
    __syncthreads();

    // ---- Phase B: W1eff build, c-matvec partials, stage hist rows ----
    for (int i = tid; i < 10240; i += 512) {
        int k = i & 127;
        sU[(i >> 7) * 136 + k] = f2b(W1bcT[i] + sQ[k] * W1dT[i]);
    }
    if (tid < 480) {
        int g = tid / 80, j = tid - g * 80;
        int kb = g * 22, ke = (kb + 22 < 128) ? kb + 22 : 128;
        float c = 0.f;
        for (int k = kb; k < ke; ++k) c = fmaf(sQ[k], W1ac[k * 80 + j], c);
        sCp[tid] = c;
    }
    for (int u = tid; u < 800; u += 512) {
        int r = u >> 2, s = u & 3;
        const float* src = (s < 2) ? (item_table + (size_t)sHist[r] * 64 + s * 32)
                                   : (cate_table + (size_t)sCid[r] * 64 + (s - 2) * 32);
        unsigned short* dst = &sA[r * 136 + s * 32];
#pragma unroll
        for (int q4 = 0; q4 < 8; ++q4) {
            float4 v = ((const float4*)src)[q4];
            ushort4 o; o.x = f2b(v.x); o.y = f2b(v.y); o.z = f2b(v.z); o.w = f2b(v.w);
            *(ushort4*)(dst + q4 * 4) = o;
        }
    }
    __syncthreads();

    if (tid < 80) {
        float c = b1[tid];
#pragma unroll
        for (int g = 0; g < 6; ++g) c += sCp[g * 80 + tid];
        sCc[tid] = c;
    }

    // ---- layer 1 MFMA: 13 M-tiles x 5 N-tiles, K=128 (4 steps) ----
    const int w = tid >> 6, l = tid & 63, lo16 = l & 15, hi = l >> 4;
    f32x4 accP[9];
#pragma unroll
    for (int pp = 0; pp < 9; ++pp) {
        int p = w + pp * 8;
        if (p < 65) {
            int mt = p / 5, nt = p - mt * 5;
            const unsigned short* Ab = &sA[(mt * 16 + lo16) * 136 + hi * 8];
            const unsigned short* Bb = &sU[(nt * 16 + lo16) * 136 + hi * 8];
            f32x4 acc = {0.f, 0.f, 0.f, 0.f};
#pragma unroll
            for (int ks = 0; ks < 4; ++ks) {
                bfrag a = *(const bfrag*)(Ab + ks * 32);
                bfrag bb = *(const bfrag*)(Bb + ks * 32);
                acc = __builtin_amdgcn_mfma_f32_16x16x32_bf16(a, bb, acc, 0, 0, 0);
            }
            accP[pp] = acc;
        }
    }
    __syncthreads();   // all W1eff reads done; sU becomes h1

    // ---- sigmoid -> h1 bf16 [208][104]; zero k-pad cols 80..95 ----
#pragma unroll
    for (int pp = 0; pp < 9; ++pp) {
        int p = w + pp * 8;
        if (p < 65) {
            int mt = p / 5, nt = p - mt * 5;
            int j = nt * 16 + lo16;
            float cc = sCc[j];
#pragma unroll
            for (int rg = 0; rg < 4; ++rg) {
                int m = mt * 16 + hi * 4 + rg;
                sU[m * 104 + j] = f2b(sigm(accP[pp][rg] + cc));
            }
        }
    }
    for (int i = tid; i < 208 * 16; i += 512) {
        int r = i >> 4;
        sU[r * 104 + 80 + (i & 15)] = 0;
    }
    __syncthreads();

    // ---- layer 2 MFMA: 13 M x 3 N tiles, K=80->96 (3 steps) + score reduce ----
#pragma unroll
    for (int pp = 0; pp < 5; ++pp) {
        int p = w + pp * 8;
        if (p < 39) {
            int mt = p / 3, nt = p - mt * 3;
            const unsigned short* Ab = &sU[(mt * 16 + lo16) * 104 + hi * 8];
            const unsigned short* Bb = &sW2[(nt * 16 + lo16) * 104 + hi * 8];
            f32x4 acc = {0.f, 0.f, 0.f, 0.f};
#pragma unroll
            for (int ks = 0; ks < 3; ++ks) {
                bfrag a = *(const bfrag*)(Ab + ks * 32);
                bfrag bb = *(const bfrag*)(Bb + ks * 32);
                acc = __builtin_amdgcn_mfma_f32_16x16x32_bf16(a, bb, acc, 0, 0, 0);
            }
            int j2 = nt * 16 + lo16;
            float w3 = sW3f[j2], b2v = sB2[j2];
#pragma unroll
            for (int rg = 0; rg < 4; ++rg) {
                float pt = sigm(acc[rg] + b2v) * w3;
                pt += __shfl_xor(pt, 1);
                pt += __shfl_xor(pt, 2);
                pt += __shfl_xor(pt, 4);
                pt += __shfl_xor(pt, 8);
                if (lo16 == 0) atomicAdd(&sScore[mt * 16 + hi * 4 + rg], pt);
            }
        }
    }
    __syncthreads();

    // ---- Phase C: masked, scaled softmax over T ----
    int t = tid;
    float sc;
    if (t < TT) {
        float raw = sScore[t] + sB3s;
        if (t >= len) raw = MASKV;
        sc = raw * INV_SQRTK;
    } else {
        sc = -3.0e38f;
    }
    float mx = sc;
#pragma unroll
    for (int o = 32; o > 0; o >>= 1) mx = fmaxf(mx, __shfl_xor(mx, o));
    if ((tid & 63) == 0) sRed[tid >> 6] = mx;
    __syncthreads();
    if (tid == 0) {
        float m2 = sRed[0];
        for (int ww = 1; ww < 8; ++ww) m2 = fmaxf(m2, sRed[ww]);
        sMS[0] = m2;
    }
    __syncthreads();
    mx = sMS[0];
    float e = (t < TT) ? __expf(sc - mx) : 0.f;
    float sum = e;
#pragma unroll
    for (int o = 32; o > 0; o >>= 1) sum += __shfl_xor(sum, o);
    if ((tid & 63) == 0) sRed[tid >> 6] = sum;
    __syncthreads();
    if (tid == 0) {
        float s2 = 0.f;
        for (int ww = 0; ww < 8; ++ww) s2 += sRed[ww];
        sMS[1] = s2;
    }
    __syncthreads();
    float inv = 1.f / sMS[1];
    if (t < TT) sScore[t] = e * inv;
    __syncthreads();

    // ---- Phase D: hist_attn[k] = sum_t attn[t]*hist[t][k] from LDS bf16 ----
    {
        const int k2 = (tid & 63) * 2;
        const int g  = tid >> 6;
        float a0 = 0.f, a1 = 0.f;
        for (int tt = g; tt < TT; tt += 8) {
            float aw = sScore[tt];
            unsigned pr = *(const unsigned*)&sA[tt * 136 + k2];
            a0 = fmaf(aw, b2f((unsigned short)(pr & 0xffffu)), a0);
            a1 = fmaf(aw, b2f((unsigned short)(pr >> 16)), a1);
        }
        sPd[g * 128 + k2]     = a0;
        sPd[g * 128 + k2 + 1] = a1;
    }
    __syncthreads();
    if (tid < 128) {
        float tot = 0.f;
#pragma unroll
        for (int g = 0; g < 8; ++g) tot += sPd[g * 128 + tid];
        hist_attn[(size_t)b * 128 + tid] = tot;
        atomicAdd(&hstats[tid], tot);
        atomicAdd(&hstats[128 + tid], tot * tot);
    }
}

// ---------------------------------------------------------------------------
// K3: hist_hid = BN(hist_attn)@hist_W + hist_b ; assemble join ; join stats
// ---------------------------------------------------------------------------
__global__ __launch_bounds__(256) void k3_histfc_join(
    const float* __restrict__ hist_attn, const float* __restrict__ hstats,
    const float* __restrict__ hgamma, const float* __restrict__ hbeta,
    const float* __restrict__ histW, const float* __restrict__ histb,
    const int* __restrict__ user, const int* __restrict__ item,
    const int* __restrict__ cate_list,
    const float* __restrict__ user_table, const float* __restrict__ item_table,
    const float* __restrict__ cate_table,
    float* __restrict__ jbuf, float* __restrict__ jstats)
{
    __shared__ float sWs[128][132];
    __shared__ float sX[8][132];
    __shared__ float sCsP[2][128];
    __shared__ float sCb[128];
    __shared__ float sScale[128];
    __shared__ float sShift[128];

    const int tid = threadIdx.x;
    const int r0  = blockIdx.x * 8;
    if (tid < 128) {
        float m  = hstats[tid] * (1.f / 2048.f);
        float v  = hstats[128 + tid] * (1.f / 2048.f) - m * m;
        float rs = rsqrtf(v + BN_EPS);
        float scv = hgamma[tid] * rs;
        sScale[tid] = scv;
        sShift[tid] = hbeta[tid] - m * scv;
        sCb[tid] = histb[tid];
    }
    __syncthreads();
    for (int i = tid; i < 128 * 128; i += 256) {
        int k = i >> 7;
        sWs[k][i & 127] = sScale[k] * histW[i];
    }
    {   // parallel c[j] = sum_k shift[k]*W[k][j]
        int j = tid & 127, g = tid >> 7;
        float c = 0.f;
        for (int k = g * 64; k < g * 64 + 64; ++k) c = fmaf(sShift[k], histW[k * 128 + j], c);
        sCsP[g][j] = c;
    }
    for (int i = tid; i < 8 * 128; i += 256) {
        int r = i >> 7;
        sX[r][i & 127] = hist_attn[(size_t)(r0 + r) * 128 + (i & 127)];
    }
    __syncthreads();

    const int j  = tid & 127;
    const int rh = tid >> 7;
    float su0 = 0.f, su1 = 0.f, su2 = 0.f, sq0 = 0.f, sq1 = 0.f, sq2 = 0.f;
    for (int r = rh; r < 8; r += 2) {
        int row = r0 + r;
        float o = sCsP[0][j] + sCsP[1][j] + sCb[j];
        for (int k = 0; k < 128; ++k) o = fmaf(sX[r][k], sWs[k][j], o);
        int u    = user[row];
        float ue = user_table[(size_t)u * 128 + j];
        int itv  = item[row];
        float qv = (j < 64) ? item_table[(size_t)itv * 64 + j]
                            : cate_table[(size_t)cate_list[itv] * 64 + (j - 64)];
        jbuf[(size_t)row * 384 + j]       = ue;
        jbuf[(size_t)row * 384 + 128 + j] = qv;
        jbuf[(size_t)row * 384 + 256 + j] = o;
        su0 += ue; sq0 = fmaf(ue, ue, sq0);
        su1 += qv; sq1 = fmaf(qv, qv, sq1);
        su2 += o;  sq2 = fmaf(o, o, sq2);
    }
    atomicAdd(&jstats[j], su0);            atomicAdd(&jstats[384 + j], sq0);
    atomicAdd(&jstats[128 + j], su1);      atomicAdd(&jstats[384 + 128 + j], sq1);
    atomicAdd(&jstats[256 + j], su2);      atomicAdd(&jstats[384 + 256 + j], sq2);
}

// ---------------------------------------------------------------------------
// K4: x = BN(join) ; pre1 = x@fc1_W + b ; pre1 column stats  (fc1WT [80][384])
// ---------------------------------------------------------------------------
__global__ __launch_bounds__(256) void k4_fc1(
    const float* __restrict__ jbuf, const float* __restrict__ jstats,
    const float* __restrict__ fgamma, const float* __restrict__ fbeta,
    const float* __restrict__ fc1WT, const float* __restrict__ fc1b,
    float* __restrict__ pre1, float* __restrict__ p1stats)
{
    __shared__ float sXn[8][388];
    __shared__ float sScale[384];
    __shared__ float sShift[384];
    const int tid = threadIdx.x;
    const int r0  = blockIdx.x * 8;
    for (int c = tid; c < 384; c += 256) {
        float m  = jstats[c] * (1.f / 2048.f);
        float v  = jstats[384 + c] * (1.f / 2048.f) - m * m;
        float rs = rsqrtf(v + BN_EPS);
        float scv = fgamma[c] * rs;
        sScale[c] = scv;
        sShift[c] = fbeta[c] - m * scv;
    }
    __syncthreads();
    for (int i = tid; i < 8 * 384; i += 256) {
        int r = i / 384, c = i - r * 384;
        sXn[r][c] = jbuf[(size_t)(r0 + r) * 384 + c] * sScale[c] + sShift[c];
    }
    __syncthreads();
    const int j1 = tid % 80;
    const int rg = tid / 80;
    if (rg < 3) {
        const float* wrow = fc1WT + (size_t)j1 * 384;
        float bias = fc1b[j1];
        float su = 0.f, sq = 0.f;
        for (int r = rg; r < 8; r += 3) {
            float a = bias;
            for (int c = 0; c < 384; c += 4) {
                float4 wv = *(const float4*)(wrow + c);
                float4 xv = *(const float4*)&sXn[r][c];
                a = fmaf(wv.x, xv.x, fmaf(wv.y, xv.y, fmaf(wv.z, xv.z, fmaf(wv.w, xv.w, a))));
            }
            pre1[(size_t)(r0 + r) * 80 + j1] = a;
            su += a;
            sq = fmaf(a, a, sq);
        }
        atomicAdd(&p1stats[j1], su);
        atomicAdd(&p1stats[80 + j1], sq);
    }
}

// ---------------------------------------------------------------------------
// K5: x1 = dice(pre1) ; pre2 = x1@fc2_W + b ; pre2 column stats (fc2WT [40][80])
// ---------------------------------------------------------------------------
__global__ __launch_bounds__(256) void k5_fc2(
    const float* __restrict__ pre1, const float* __restrict__ p1stats,
    const float* __restrict__ d1a, const float* __restrict__ d1b,
    const float* __restrict__ fc2WT, const float* __restrict__ fc2b,
    float* __restrict__ pre2, float* __restrict__ p2stats)
{
    __shared__ float sX1[8][84];
    __shared__ float sM[80], sRs[80], sA[80], sBt[80];
    const int tid = threadIdx.x;
    const int r0  = blockIdx.x * 8;
    if (tid < 80) {
        float m = p1stats[tid] * (1.f / 2048.f);
        float v = p1stats[80 + tid] * (1.f / 2048.f) - m * m;
        sM[tid]  = m;
        sRs[tid] = rsqrtf(v + BN_EPS);
        sA[tid]  = d1a[tid];
        sBt[tid] = d1b[tid];
    }
    __syncthreads();
    for (int i = tid; i < 8 * 80; i += 256) {
        int r = i / 80, c = i - r * 80;
        float x  = pre1[(size_t)(r0 + r) * 80 + c];
        float xn = (x - sM[c]) * sRs[c];
        float p  = sigm(sBt[c] * xn);
        sX1[r][c] = x * (p + sA[c] * (1.f - p));
    }
    __syncthreads();
    const int j2 = tid % 40;
    const int rg = tid / 40;
    if (rg < 6) {
        const float* wrow = fc2WT + (size_t)j2 * 80;
        float bias = fc2b[j2];
        float su = 0.f, sq = 0.f;
        for (int r = rg; r < 8; r += 6) {
            float a = bias;
            for (int c = 0; c < 80; c += 4) {
                float4 wv = *(const float4*)(wrow + c);
                float4 xv = *(const float4*)&sX1[r][c];
                a = fmaf(wv.x, xv.x, fmaf(wv.y, xv.y, fmaf(wv.z, xv.z, fmaf(wv.w, xv.w, a))));
            }
            pre2[(size_t)(r0 + r) * 40 + j2] = a;
            su += a;
            sq = fmaf(a, a, sq);
        }
        atomicAdd(&p2stats[j2], su);
        atomicAdd(&p2stats[40 + j2], sq);
    }
}

// ---------------------------------------------------------------------------
// K6: x2 = dice(pre2) ; out = x2@fc3_W + b3 + item_bias ; logit = sigmoid(out)
// ---------------------------------------------------------------------------
__global__ __launch_bounds__(256) void k6_out(
    const float* __restrict__ pre2, const float* __restrict__ p2stats,
    const float* __restrict__ d2a, const float* __restrict__ d2b,
    const float* __restrict__ fc3W, const float* __restrict__ fc3b,
    const float* __restrict__ item_bias, const int* __restrict__ item,
    float* __restrict__ outp)
{
    __shared__ float sP[256 * 41];
    __shared__ float sM[40], sRs[40], sA[40], sBt[40], sW[40];
    __shared__ float sB3v;
    const int tid = threadIdx.x;
    const int r0  = blockIdx.x * 256;
    if (tid < 40) {
        float m = p2stats[tid] * (1.f / 2048.f);
        float v = p2stats[40 + tid] * (1.f / 2048.f) - m * m;
        sM[tid]  = m;
        sRs[tid] = rsqrtf(v + BN_EPS);
        sA[tid]  = d2a[tid];
        sBt[tid] = d2b[tid];
        sW[tid]  = fc3W[tid];
    }
    if (tid == 0) sB3v = fc3b[0];
    for (int i = tid; i < 256 * 40; i += 256) {
        int r = i / 40, c = i - r * 40;
        sP[r * 41 + c] = pre2[(size_t)(r0 + r) * 40 + c];
    }
    __syncthreads();
    const int r = r0 + tid;
    float a = sB3v;
    for (int c = 0; c < 40; ++c) {
        float x  = sP[tid * 41 + c];
        float xn = (x - sM[c]) * sRs[c];
        float p  = sigm(sBt[c] * xn);
        float x2 = x * (p + sA[c] * (1.f - p));
        a = fmaf(x2, sW[c], a);
    }
    a += item_bias[item[r]];
    outp[r]      = a;
    outp[BB + r] = sigm(a);
}

// ---------------------------------------------------------------------------
extern "C" void kernel_launch(void* const* d_in, const int* in_sizes, int n_in,
                              void* d_out, int out_size, void* d_ws, size_t ws_size,
                              hipStream_t stream)
{
    const int*   user       = (const int*)d_in[0];
    const int*   item       = (const int*)d_in[1];
    const int*   history    = (const int*)d_in[2];
    const int*   length     = (const int*)d_in[3];
    const int*   cate_list  = (const int*)d_in[4];
    const float* user_table = (const float*)d_in[5];
    const float* item_table = (const float*)d_in[6];
    const float* cate_table = (const float*)d_in[7];
    const float* item_bias  = (const float*)d_in[8];
    const float* att_W1 = (const float*)d_in[9];
    const float* att_b1 = (const float*)d_in[10];
    const float* att_W2 = (const float*)d_in[11];
    const float* att_b2 = (const float*)d_in[12];
    const float* att_W3 = (const float*)d_in[13];
    const float* att_b3 = (const float*)d_in[14];
    const float* hgam   = (const float*)d_in[15];
    const float* hbet   = (const float*)d_in[16];
    const float* histW  = (const float*)d_in[17];
    const float* histb  = (const float*)d_in[18];
    const float* fgam   = (const float*)d_in[19];
    const float* fbet   = (const float*)d_in[20];
    const float* fc1W   = (const float*)d_in[21];
    const float* fc1b   = (const float*)d_in[22];
    const float* d1a    = (const float*)d_in[23];
    const float* d1b    = (const float*)d_in[24];
    const float* fc2W   = (const float*)d_in[25];
    const float* fc2b   = (const float*)d_in[26];
    const float* d2a    = (const float*)d_in[27];
    const float* d2b    = (const float*)d_in[28];
    const float* fc3W   = (const float*)d_in[29];
    const float* fc3b   = (const float*)d_in[30];

    float* ws        = (float*)d_ws;
    float* hist_attn = ws;                    // 2048*128 = 262144
    float* jbuf      = hist_attn + 262144;    // 2048*384 = 786432
    float* pre1      = jbuf + 786432;         // 2048*80  = 163840
    float* pre2      = pre1 + 163840;         // 2048*40  = 81920
    float* stats     = pre2 + 81920;          // 1264
    float* hstats  = stats;                   // 256
    float* jstats  = stats + 256;             // 768
    float* p1stats = jstats + 768;            // 160
    float* p2stats = p1stats + 160;           // 80
    float* prep    = stats + 1264;            // 64640
    float* W1bcT = prep;
    float* W1dT  = prep + 10240;
    float* W1ac  = prep + 20480;
    float* fc1WT = prep + 30720;
    float* fc2WT = prep + 61440;

    hipMemsetAsync(stats, 0, 1264 * sizeof(float), stream);

    k0_prep<<<128, 256, 0, stream>>>(att_W1, fc1W, fc2W, prep);

    k1_attn<<<BB, 512, 0, stream>>>(item, history, length, cate_list,
        item_table, cate_table, W1bcT, W1dT, W1ac,
        att_b1, att_W2, att_b2, att_W3, att_b3,
        hist_attn, hstats);

    k3_histfc_join<<<256, 256, 0, stream>>>(hist_attn, hstats, hgam, hbet,
        histW, histb, user, item, cate_list, user_table, item_table, cate_table,
        jbuf, jstats);
    k4_fc1<<<256, 256, 0, stream>>>(jbuf, jstats, fgam, fbet, fc1WT, fc1b,
        pre1, p1stats);
    k5_fc2<<<256, 256, 0, stream>>>(pre1, p1stats, d1a, d1b, fc2WT, fc2b,
        pre2, p2stats);
    k6_out<<<8, 256, 0, stream>>>(pre2, p2stats, d2a, d2b, fc3W, fc3b,
        item_bias, item, (float*)d_out);
}